// Round 4
// baseline (2294.629 us; speedup 1.0000x reference)
//
#include <hip/hip_runtime.h>
#include <hip/hip_bf16.h>
#include <math.h>

// SimilarityTreeLSTM on MI355X — round 4: single fused kernel, manual grid
// barrier (round 3's hipLaunchCooperativeKernel failed to launch; identical
// all-zeros output signature). 256 blocks x 256 threads: co-residency is
// guaranteed (every block fits any CU, 256 blocks <= 256 CUs), so a
// monotonic atomic-counter barrier with agent-scope fences is safe.
//
// Levels (j = 511-i, complete 4-ary heap):
//   ph0 [0,171) ph1 [171,427) ph2 [427,491) ph3 [491,507) ph4 [507,511) ph5 [511,512)
// Pad child index 512 -> per-tree zero row; state buffers [2][513][512].
//
// Phase block = 32 rows x 128 cols; wave owns 32 cols: iou (3 gate slices)
// + f (128 child-rows) via mfma_f32_16x16x32_bf16, gating fused in-register;
// f-sums cross the C-layout lane permutation via per-wave LDS transpose.

typedef __attribute__((ext_vector_type(8))) __bf16 bf16x8;
typedef __attribute__((ext_vector_type(4))) float f32x4;
typedef unsigned short u16;

#define NB 256

struct Params {
    const int *lin, *rin, *lch, *rch;
    const float *emb, *W_ioux, *b_ioux, *W_iouh, *b_iouh;
    const float *W_fx, *b_fx, *W_fh, *b_fh, *Wh, *bh, *Wp, *bp;
    float* out;
    u16 *WiouhT, *WfhT, *WxT, *Whb, *xcat, *hbf;
    float *cbuf, *hid_raw;
    unsigned* bar;
};

__device__ __forceinline__ float sigm(float x) { return 1.0f / (1.0f + __expf(-x)); }
__device__ __forceinline__ u16 f2bf(float f) {
    union { float f; unsigned int u; } v; v.f = f;
    unsigned int r = v.u + 0x7FFF + ((v.u >> 16) & 1);
    return (u16)(r >> 16);
}
__device__ __forceinline__ float bf2f(u16 b) {
    union { unsigned int u; float f; } v; v.u = ((unsigned int)b) << 16;
    return v.f;
}
__device__ __forceinline__ f32x4 mfma16(bf16x8 a, bf16x8 b, f32x4 c) {
    return __builtin_amdgcn_mfma_f32_16x16x32_bf16(a, b, c, 0, 0, 0);
}
__device__ __forceinline__ bf16x8 load_f32_as_bf8(const float* p) {
    float4 x = *(const float4*)p;
    float4 y = *(const float4*)(p + 4);
    bf16x8 r;
    r[0] = (__bf16)x.x; r[1] = (__bf16)x.y; r[2] = (__bf16)x.z; r[3] = (__bf16)x.w;
    r[4] = (__bf16)y.x; r[5] = (__bf16)y.y; r[6] = (__bf16)y.z; r[7] = (__bf16)y.w;
    return r;
}

// Manual grid barrier: monotonic counter, device(agent)-scope atomics.
// target = NB * (number of barriers passed so far, incl. this one).
__device__ __forceinline__ void gridbar(unsigned* bar, unsigned target)
{
    __threadfence();                       // release: make prior writes device-visible
    __syncthreads();
    if (threadIdx.x == 0) {
        __hip_atomic_fetch_add(bar, 1u, __ATOMIC_ACQ_REL, __HIP_MEMORY_SCOPE_AGENT);
        while (__hip_atomic_load(bar, __ATOMIC_ACQUIRE, __HIP_MEMORY_SCOPE_AGENT) < target)
            __builtin_amdgcn_s_sleep(1);
    }
    __syncthreads();
    __threadfence();                       // acquire: invalidate stale L1
}

__global__ __launch_bounds__(256)
void fused(Params P)
{
    __shared__ float smem[4][32][33];
    const int bb = blockIdx.x, tid = threadIdx.x;
    const int w = tid >> 6, lane = tid & 63, m = lane & 15, q = lane >> 4;
    unsigned tgt = 0;

    // ================= S0: weight transpose/convert + zero init ============
    {
        const int tx = tid & 31, ty = tid >> 5;
#pragma unroll 1
        for (int u = 0; u < 8; ++u) {
            const int tt = bb * 8 + u;
            const float* src; u16* dst; int lds_, k0, n0;
            if (tt < 768)       { src = P.W_ioux; lds_ = 1536; dst = P.WxT;
                                  k0 = (tt & 15) * 32; n0 = (tt >> 4) * 32; }
            else if (tt < 1024) { const int t2 = tt - 768; src = P.W_fx; lds_ = 512;
                                  dst = P.WxT + (size_t)1536 * 512;
                                  k0 = (t2 & 15) * 32; n0 = (t2 >> 4) * 32; }
            else if (tt < 1792) { const int t2 = tt - 1024; src = P.W_iouh; lds_ = 1536;
                                  dst = P.WiouhT; k0 = (t2 & 15) * 32; n0 = (t2 >> 4) * 32; }
            else                { const int t2 = tt - 1792; src = P.W_fh; lds_ = 512;
                                  dst = P.WfhT; k0 = (t2 & 15) * 32; n0 = (t2 >> 4) * 32; }
            __syncthreads();
#pragma unroll
            for (int i = 0; i < 4; ++i)
                smem[0][ty + 8 * i][tx] = src[(size_t)(k0 + ty + 8 * i) * lds_ + n0 + tx];
            __syncthreads();
#pragma unroll
            for (int i = 0; i < 4; ++i)
                dst[(size_t)(n0 + ty + 8 * i) * 512 + k0 + tx] = f2bf(smem[0][tx][ty + 8 * i]);
        }
        const size_t base = (size_t)bb * 2048 + tid;
#pragma unroll
        for (int i = 0; i < 8; ++i) P.Whb[base + 256 * i] = f2bf(P.Wh[base + 256 * i]);
        if (bb == 0) {
            for (int i = tid; i < 512; i += 256) {
                P.hbf[(size_t)512 * 512 + i] = 0;
                P.hbf[(size_t)1025 * 512 + i] = 0;
                P.cbuf[(size_t)512 * 512 + i] = 0.f;
                P.cbuf[(size_t)1025 * 512 + i] = 0.f;
                P.hid_raw[i] = 0.f;
            }
        }
    }
    gridbar(P.bar, tgt += NB);

    // ================= S1: prege — xcat[1024][2048] = bf16(emb[tok])@WxT^T + b
    {
        const int mt = bb & 31, nb = bb >> 5;
        const int colbase = nb * 256 + w * 64;
        const int r0 = mt * 32 + m, r1 = r0 + 16;
        const int tok0 = (r0 < 512) ? P.lin[r0] : P.rin[r0 - 512];
        const int tok1 = (r1 < 512) ? P.lin[r1] : P.rin[r1 - 512];
        const float* A0 = P.emb + (size_t)tok0 * 512;
        const float* A1 = P.emb + (size_t)tok1 * 512;
        f32x4 acc[2][4];
#pragma unroll
        for (int i = 0; i < 2; ++i)
#pragma unroll
            for (int j = 0; j < 4; ++j) acc[i][j] = (f32x4){0.f, 0.f, 0.f, 0.f};
        for (int k0 = 0; k0 < 512; k0 += 32) {
            const int koff = k0 + q * 8;
            bf16x8 a0 = load_f32_as_bf8(A0 + koff);
            bf16x8 a1 = load_f32_as_bf8(A1 + koff);
#pragma unroll
            for (int jj = 0; jj < 4; ++jj) {
                bf16x8 b = *(const bf16x8*)(P.WxT + (size_t)(colbase + jj * 16 + m) * 512 + koff);
                acc[0][jj] = mfma16(a0, b, acc[0][jj]);
                acc[1][jj] = mfma16(a1, b, acc[1][jj]);
            }
        }
#pragma unroll
        for (int i = 0; i < 2; ++i)
#pragma unroll
            for (int jj = 0; jj < 4; ++jj)
#pragma unroll
                for (int rr = 0; rr < 4; ++rr) {
                    const int R = mt * 32 + i * 16 + q * 4 + rr;
                    const int col = colbase + jj * 16 + m;
                    const float bias = (col < 1536) ? P.b_ioux[col] : P.b_fx[col - 1536];
                    P.xcat[(size_t)R * 2048 + col] = f2bf(acc[i][jj][rr] + bias);
                }
    }
    gridbar(P.bar, tgt += NB);

    // ================= phases 0..5: fused gather + dual GEMM + gating ======
    constexpr int los[6] = {0, 171, 427, 491, 507, 511};
    constexpr int Bsz[6] = {171, 256, 64, 16, 4, 1};
#pragma unroll 1
    for (int ph = 0; ph < 6; ++ph) {
        const int lo = los[ph], B = Bsz[ph], B2 = 2 * B;
        const int RG = (B2 + 31) >> 5;
        if (bb < RG * 4) {
            const int rg = bb >> 2, cgp = bb & 3;
            const int colbase = cgp * 128 + w * 32;

            const u16* hpA[2][4];
#pragma unroll
            for (int Mi = 0; Mi < 2; ++Mi) {
                const int r = rg * 32 + Mi * 16 + m;
                int tree = 0, c0 = 512, c1 = 512, c2 = 512, c3 = 512;
                if (r < B2) {
                    tree = (r >= B) ? 1 : 0;
                    const int j = lo + r - tree * B;
                    const int* ch = (tree ? P.rch : P.lch) + 4 * j;
                    c0 = ch[0]; c1 = ch[1]; c2 = ch[2]; c3 = ch[3];
                }
                const u16* hb = P.hbf + (size_t)tree * 513 * 512;
                hpA[Mi][0] = hb + (size_t)c0 * 512; hpA[Mi][1] = hb + (size_t)c1 * 512;
                hpA[Mi][2] = hb + (size_t)c2 * 512; hpA[Mi][3] = hb + (size_t)c3 * 512;
            }
            const u16* fpA[8];
#pragma unroll
            for (int Ft = 0; Ft < 8; ++Ft) {
                const int fr = Ft * 16 + m;
                const int r = rg * 32 + (fr >> 2), s = fr & 3;
                int tree = 0, c = 512;
                if (r < B2) {
                    tree = (r >= B) ? 1 : 0;
                    const int j = lo + r - tree * B;
                    c = ((tree ? P.rch : P.lch) + 4 * j)[s];
                }
                fpA[Ft] = P.hbf + ((size_t)tree * 513 + c) * 512;
            }
            const u16* pBi[3][2]; const u16* pBf[2];
#pragma unroll
            for (int g = 0; g < 3; ++g)
#pragma unroll
                for (int Nj = 0; Nj < 2; ++Nj)
                    pBi[g][Nj] = P.WiouhT + (size_t)(g * 512 + colbase + Nj * 16 + m) * 512;
#pragma unroll
            for (int Nj = 0; Nj < 2; ++Nj)
                pBf[Nj] = P.WfhT + (size_t)(colbase + Nj * 16 + m) * 512;

            f32x4 aci[3][2][2];
            f32x4 acf[8][2];
#pragma unroll
            for (int g = 0; g < 3; ++g)
#pragma unroll
                for (int Mi = 0; Mi < 2; ++Mi)
#pragma unroll
                    for (int Nj = 0; Nj < 2; ++Nj) aci[g][Mi][Nj] = (f32x4){0.f, 0.f, 0.f, 0.f};
#pragma unroll
            for (int Ft = 0; Ft < 8; ++Ft)
#pragma unroll
                for (int Nj = 0; Nj < 2; ++Nj) acf[Ft][Nj] = (f32x4){0.f, 0.f, 0.f, 0.f};

#pragma unroll 1
            for (int k0 = 0; k0 < 512; k0 += 32) {
                const int koff = k0 + q * 8;
                bf16x8 ah[2];
#pragma unroll
                for (int Mi = 0; Mi < 2; ++Mi) {
                    float s0[8] = {0.f, 0.f, 0.f, 0.f, 0.f, 0.f, 0.f, 0.f};
#pragma unroll
                    for (int s = 0; s < 4; ++s) {
                        bf16x8 v = *(const bf16x8*)(hpA[Mi][s] + koff);
#pragma unroll
                        for (int t = 0; t < 8; ++t) s0[t] += (float)v[t];
                    }
                    bf16x8 a;
#pragma unroll
                    for (int t = 0; t < 8; ++t) a[t] = (__bf16)s0[t];
                    ah[Mi] = a;
                }
                bf16x8 af[8];
#pragma unroll
                for (int Ft = 0; Ft < 8; ++Ft) af[Ft] = *(const bf16x8*)(fpA[Ft] + koff);
#pragma unroll
                for (int Nj = 0; Nj < 2; ++Nj) {
#pragma unroll
                    for (int g = 0; g < 3; ++g) {
                        bf16x8 b = *(const bf16x8*)(pBi[g][Nj] + koff);
                        aci[g][0][Nj] = mfma16(ah[0], b, aci[g][0][Nj]);
                        aci[g][1][Nj] = mfma16(ah[1], b, aci[g][1][Nj]);
                    }
                    bf16x8 b2 = *(const bf16x8*)(pBf[Nj] + koff);
#pragma unroll
                    for (int Ft = 0; Ft < 8; ++Ft) acf[Ft][Nj] = mfma16(af[Ft], b2, acf[Ft][Nj]);
                }
            }

            // f epilogue: lane (q,m) owns node R=4*Ft+q, child=reg, col=Nj*16+m
#pragma unroll
            for (int Ft = 0; Ft < 8; ++Ft) {
                const int R = 4 * Ft + q;
                const int r = rg * 32 + R;
                int tree = 0, j = lo, cc0 = 512, cc1 = 512, cc2 = 512, cc3 = 512;
                if (r < B2) {
                    tree = (r >= B) ? 1 : 0;
                    j = lo + r - tree * B;
                    const int* ch = (tree ? P.rch : P.lch) + 4 * j;
                    cc0 = ch[0]; cc1 = ch[1]; cc2 = ch[2]; cc3 = ch[3];
                }
                const float* cb = P.cbuf + (size_t)tree * 513 * 512;
#pragma unroll
                for (int Nj = 0; Nj < 2; ++Nj) {
                    const int C = colbase + Nj * 16 + m;
                    const float xf = bf2f(P.xcat[(size_t)(tree * 512 + j) * 2048 + 1536 + C]);
                    const float bfh = P.b_fh[C] + xf;
                    float fs = sigm(acf[Ft][Nj][0] + bfh) * cb[(size_t)cc0 * 512 + C]
                             + sigm(acf[Ft][Nj][1] + bfh) * cb[(size_t)cc1 * 512 + C]
                             + sigm(acf[Ft][Nj][2] + bfh) * cb[(size_t)cc2 * 512 + C]
                             + sigm(acf[Ft][Nj][3] + bfh) * cb[(size_t)cc3 * 512 + C];
                    smem[w][R][Nj * 16 + m] = fs;
                }
            }
            __syncthreads();
            // gating epilogue: lane (q,m), row R = Mi*16+q*4+rr
#pragma unroll
            for (int Mi = 0; Mi < 2; ++Mi)
#pragma unroll
                for (int rr = 0; rr < 4; ++rr) {
                    const int R = Mi * 16 + q * 4 + rr;
                    const int r = rg * 32 + R;
                    if (r >= B2) continue;
                    const int tree = (r >= B) ? 1 : 0;
                    const int j = lo + r - tree * B;
                    const size_t xrow = (size_t)(tree * 512 + j) * 2048;
#pragma unroll
                    for (int Nj = 0; Nj < 2; ++Nj) {
                        const int C = colbase + Nj * 16 + m;
                        const float ii = aci[0][Mi][Nj][rr] + P.b_iouh[C]        + bf2f(P.xcat[xrow + C]);
                        const float oo = aci[1][Mi][Nj][rr] + P.b_iouh[512 + C]  + bf2f(P.xcat[xrow + 512 + C]);
                        const float uu = aci[2][Mi][Nj][rr] + P.b_iouh[1024 + C] + bf2f(P.xcat[xrow + 1024 + C]);
                        const float ig = sigm(ii), og = sigm(oo), ug = tanhf(uu);
                        const float cv = ig * ug + smem[w][R][Nj * 16 + m];
                        P.cbuf[((size_t)tree * 513 + j) * 512 + C] = cv;
                        P.hbf[((size_t)tree * 513 + j) * 512 + C] = f2bf(og * tanhf(cv));
                    }
                }
        }
        gridbar(P.bar, tgt += NB);
    }

    // ================= head1: hid_raw[col] += vec @ Wh ======================
    if (bb < 64) {
        const float* lc = P.cbuf + (size_t)511 * 512;
        const float* rc = P.cbuf + (size_t)(513 + 511) * 512;
        const int cg8 = bb & 7, kg = bb >> 3;
        const int col = cg8 * 64 + lane;
        const int kbase = kg * 128 + w * 32;
        float acc = 0.f;
#pragma unroll 8
        for (int i = 0; i < 32; ++i) {
            const int k = kbase + i;
            float v;
            if (k < 512) v = lc[k] * rc[k];
            else { const int kk = k - 512; v = fabsf(lc[kk] - rc[kk]); }
            acc += v * bf2f(P.Whb[(size_t)k * 512 + col]);
        }
        smem[w][0][lane] = acc;
        __syncthreads();
        if (w == 0)
            atomicAdd(&P.hid_raw[col],
                      smem[0][0][lane] + smem[1][0][lane] + smem[2][0][lane] + smem[3][0][lane]);
    }
    gridbar(P.bar, tgt += NB);

    // ================= head2: log_softmax(sigm(hid)@Wp + bp) ================
    if (bb == 0) {
        float a[5] = {0.f, 0.f, 0.f, 0.f, 0.f};
        for (int k = tid; k < 512; k += 256) {
            const float hv = sigm(P.hid_raw[k] + P.bh[k]);
#pragma unroll
            for (int cc = 0; cc < 5; ++cc) a[cc] += hv * P.Wp[(size_t)k * 5 + cc];
        }
#pragma unroll
        for (int cc = 0; cc < 5; ++cc)
            for (int off = 32; off; off >>= 1) a[cc] += __shfl_xor(a[cc], off, 64);
        if (lane == 0)
#pragma unroll
            for (int cc = 0; cc < 5; ++cc) smem[w][1][cc] = a[cc];
        __syncthreads();
        if (tid == 0) {
            float lg[5], mx = -1e30f;
#pragma unroll
            for (int cc = 0; cc < 5; ++cc) {
                lg[cc] = smem[0][1][cc] + smem[1][1][cc] + smem[2][1][cc] + smem[3][1][cc] + P.bp[cc];
                mx = fmaxf(mx, lg[cc]);
            }
            float s = 0.f;
#pragma unroll
            for (int cc = 0; cc < 5; ++cc) s += __expf(lg[cc] - mx);
            const float lse = mx + __logf(s);
#pragma unroll
            for (int cc = 0; cc < 5; ++cc) P.out[cc] = lg[cc] - lse;
        }
    }
}

// ---------------- launch ----------------------------------------------------
extern "C" void kernel_launch(void* const* d_in, const int* in_sizes, int n_in,
                              void* d_out, int out_size, void* d_ws, size_t ws_size,
                              hipStream_t stream)
{
    Params P;
    P.lin    = (const int*)d_in[0];
    P.rin    = (const int*)d_in[1];
    P.lch    = (const int*)d_in[2];
    P.rch    = (const int*)d_in[3];
    P.emb    = (const float*)d_in[4];
    P.W_ioux = (const float*)d_in[5];
    P.b_ioux = (const float*)d_in[6];
    P.W_iouh = (const float*)d_in[7];
    P.b_iouh = (const float*)d_in[8];
    P.W_fx   = (const float*)d_in[9];
    P.b_fx   = (const float*)d_in[10];
    P.W_fh   = (const float*)d_in[11];
    P.b_fh   = (const float*)d_in[12];
    P.Wh     = (const float*)d_in[13];
    P.bh     = (const float*)d_in[14];
    P.Wp     = (const float*)d_in[15];
    P.bp     = (const float*)d_in[16];
    P.out    = (float*)d_out;
    (void)ws_size; (void)n_in; (void)in_sizes; (void)out_size;

    char* p = (char*)d_ws;
    P.WiouhT  = (u16*)p;   p += (size_t)1536 * 512 * 2;
    P.WfhT    = (u16*)p;   p += (size_t)512 * 512 * 2;
    P.WxT     = (u16*)p;   p += (size_t)2048 * 512 * 2;
    P.Whb     = (u16*)p;   p += (size_t)1024 * 512 * 2;
    P.xcat    = (u16*)p;   p += (size_t)1024 * 2048 * 2;
    P.hbf     = (u16*)p;   p += (size_t)2 * 513 * 512 * 2;
    P.cbuf    = (float*)p; p += (size_t)2 * 513 * 512 * 4;
    P.hid_raw = (float*)p; p += (size_t)512 * 4;
    P.bar     = (unsigned*)p; p += 64;

    hipMemsetAsync(P.bar, 0, sizeof(unsigned), stream);
    fused<<<NB, 256, 0, stream>>>(P);
}

// Round 5
// 589.934 us; speedup vs baseline: 3.8896x; 3.8896x over previous
//
#include <hip/hip_runtime.h>
#include <hip/hip_bf16.h>
#include <math.h>

// SimilarityTreeLSTM on MI355X — round 5: fused kernel (round-4 compute,
// verified) + cheap grid barrier.
//
// Round-4 barrier pathology: per-wave __threadfence (2048 wbl2/inv per
// barrier) + ACQUIRE spin load (buffer_inv sc1 EVERY poll iteration from 256
// blocks) -> continuous full-L2 invalidation storm, 233 us/barrier. Fix:
// tid0-only single release fence -> relaxed add -> RELAXED spin (no inv) ->
// single acquire fence. __syncthreads drains vmcnt (write-through L1 ->
// stores are in L2 before the fence), so one wbl2 per block covers the
// block's writes; one buffer_inv on exit covers the CU's L1 + XCD L2.
//
// Levels (j = 511-i, complete 4-ary heap):
//   ph0 [0,171) ph1 [171,427) ph2 [427,491) ph3 [491,507) ph4 [507,511) ph5 [511,512)
// Pad child index 512 -> per-tree zero row; state buffers [2][513][512].

typedef __attribute__((ext_vector_type(8))) __bf16 bf16x8;
typedef __attribute__((ext_vector_type(4))) float f32x4;
typedef unsigned short u16;

#define NB 256

struct Params {
    const int *lin, *rin, *lch, *rch;
    const float *emb, *W_ioux, *b_ioux, *W_iouh, *b_iouh;
    const float *W_fx, *b_fx, *W_fh, *b_fh, *Wh, *bh, *Wp, *bp;
    float* out;
    u16 *WiouhT, *WfhT, *WxT, *xcat, *hbf;
    float *cbuf, *hid_raw;
    unsigned* bar;
};

__device__ __forceinline__ float sigm(float x) { return 1.0f / (1.0f + __expf(-x)); }
__device__ __forceinline__ u16 f2bf(float f) {
    union { float f; unsigned int u; } v; v.f = f;
    unsigned int r = v.u + 0x7FFF + ((v.u >> 16) & 1);
    return (u16)(r >> 16);
}
__device__ __forceinline__ float bf2f(u16 b) {
    union { unsigned int u; float f; } v; v.u = ((unsigned int)b) << 16;
    return v.f;
}
__device__ __forceinline__ f32x4 mfma16(bf16x8 a, bf16x8 b, f32x4 c) {
    return __builtin_amdgcn_mfma_f32_16x16x32_bf16(a, b, c, 0, 0, 0);
}
__device__ __forceinline__ bf16x8 load_f32_as_bf8(const float* p) {
    float4 x = *(const float4*)p;
    float4 y = *(const float4*)(p + 4);
    bf16x8 r;
    r[0] = (__bf16)x.x; r[1] = (__bf16)x.y; r[2] = (__bf16)x.z; r[3] = (__bf16)x.w;
    r[4] = (__bf16)y.x; r[5] = (__bf16)y.y; r[6] = (__bf16)y.z; r[7] = (__bf16)y.w;
    return r;
}

// Grid barrier: monotonic counter; single release/acquire fence per block;
// RELAXED spin (no per-iteration cache invalidation).
__device__ __forceinline__ void gridbar(unsigned* bar, unsigned target)
{
    __syncthreads();   // all waves' stores drained to L2 (vmcnt(0) before s_barrier)
    if (threadIdx.x == 0) {
        __builtin_amdgcn_fence(__ATOMIC_RELEASE, "agent");   // wb this XCD's L2
        __hip_atomic_fetch_add(bar, 1u, __ATOMIC_RELAXED, __HIP_MEMORY_SCOPE_AGENT);
        while (__hip_atomic_load(bar, __ATOMIC_RELAXED, __HIP_MEMORY_SCOPE_AGENT) < target)
            __builtin_amdgcn_s_sleep(2);
        __builtin_amdgcn_fence(__ATOMIC_ACQUIRE, "agent");   // inv L1 + stale L2
    }
    __syncthreads();
}

__global__ __launch_bounds__(256)
void fused(Params P)
{
    __shared__ float smem[4][32][33];
    const int bb = blockIdx.x, tid = threadIdx.x;
    const int w = tid >> 6, lane = tid & 63, m = lane & 15, q = lane >> 4;
    unsigned tgt = 0;

    // ================= S0: weight transpose/convert + zero init ============
    {
        const int tx = tid & 31, ty = tid >> 5;
#pragma unroll 1
        for (int u = 0; u < 8; ++u) {
            const int tt = bb * 8 + u;
            const float* src; u16* dst; int lds_, k0, n0;
            if (tt < 768)       { src = P.W_ioux; lds_ = 1536; dst = P.WxT;
                                  k0 = (tt & 15) * 32; n0 = (tt >> 4) * 32; }
            else if (tt < 1024) { const int t2 = tt - 768; src = P.W_fx; lds_ = 512;
                                  dst = P.WxT + (size_t)1536 * 512;
                                  k0 = (t2 & 15) * 32; n0 = (t2 >> 4) * 32; }
            else if (tt < 1792) { const int t2 = tt - 1024; src = P.W_iouh; lds_ = 1536;
                                  dst = P.WiouhT; k0 = (t2 & 15) * 32; n0 = (t2 >> 4) * 32; }
            else                { const int t2 = tt - 1792; src = P.W_fh; lds_ = 512;
                                  dst = P.WfhT; k0 = (t2 & 15) * 32; n0 = (t2 >> 4) * 32; }
            __syncthreads();
#pragma unroll
            for (int i = 0; i < 4; ++i)
                smem[0][ty + 8 * i][tx] = src[(size_t)(k0 + ty + 8 * i) * lds_ + n0 + tx];
            __syncthreads();
#pragma unroll
            for (int i = 0; i < 4; ++i)
                dst[(size_t)(n0 + ty + 8 * i) * 512 + k0 + tx] = f2bf(smem[0][tx][ty + 8 * i]);
        }
        if (bb == 0) {
            for (int i = tid; i < 512; i += 256) {
                P.hbf[(size_t)512 * 512 + i] = 0;
                P.hbf[(size_t)1025 * 512 + i] = 0;
                P.cbuf[(size_t)512 * 512 + i] = 0.f;
                P.cbuf[(size_t)1025 * 512 + i] = 0.f;
                P.hid_raw[i] = 0.f;
            }
        }
    }
    gridbar(P.bar, tgt += NB);

    // ================= S1: prege — xcat[1024][2048] = bf16(emb[tok])@WxT^T + b
    {
        const int mt = bb & 31, nb = bb >> 5;
        const int colbase = nb * 256 + w * 64;
        const int r0 = mt * 32 + m, r1 = r0 + 16;
        const int tok0 = (r0 < 512) ? P.lin[r0] : P.rin[r0 - 512];
        const int tok1 = (r1 < 512) ? P.lin[r1] : P.rin[r1 - 512];
        const float* A0 = P.emb + (size_t)tok0 * 512;
        const float* A1 = P.emb + (size_t)tok1 * 512;
        f32x4 acc[2][4];
#pragma unroll
        for (int i = 0; i < 2; ++i)
#pragma unroll
            for (int j = 0; j < 4; ++j) acc[i][j] = (f32x4){0.f, 0.f, 0.f, 0.f};
        for (int k0 = 0; k0 < 512; k0 += 32) {
            const int koff = k0 + q * 8;
            bf16x8 a0 = load_f32_as_bf8(A0 + koff);
            bf16x8 a1 = load_f32_as_bf8(A1 + koff);
#pragma unroll
            for (int jj = 0; jj < 4; ++jj) {
                bf16x8 b = *(const bf16x8*)(P.WxT + (size_t)(colbase + jj * 16 + m) * 512 + koff);
                acc[0][jj] = mfma16(a0, b, acc[0][jj]);
                acc[1][jj] = mfma16(a1, b, acc[1][jj]);
            }
        }
#pragma unroll
        for (int i = 0; i < 2; ++i)
#pragma unroll
            for (int jj = 0; jj < 4; ++jj)
#pragma unroll
                for (int rr = 0; rr < 4; ++rr) {
                    const int R = mt * 32 + i * 16 + q * 4 + rr;
                    const int col = colbase + jj * 16 + m;
                    const float bias = (col < 1536) ? P.b_ioux[col] : P.b_fx[col - 1536];
                    P.xcat[(size_t)R * 2048 + col] = f2bf(acc[i][jj][rr] + bias);
                }
    }
    gridbar(P.bar, tgt += NB);

    // ================= phases 0..5: fused gather + dual GEMM + gating ======
    constexpr int los[6] = {0, 171, 427, 491, 507, 511};
    constexpr int Bsz[6] = {171, 256, 64, 16, 4, 1};
#pragma unroll 1
    for (int ph = 0; ph < 6; ++ph) {
        const int lo = los[ph], B = Bsz[ph], B2 = 2 * B;
        const int RG = (B2 + 31) >> 5;
        if (bb < RG * 4) {
            const int rg = bb >> 2, cgp = bb & 3;
            const int colbase = cgp * 128 + w * 32;

            const u16* hpA[2][4];
#pragma unroll
            for (int Mi = 0; Mi < 2; ++Mi) {
                const int r = rg * 32 + Mi * 16 + m;
                int tree = 0, c0 = 512, c1 = 512, c2 = 512, c3 = 512;
                if (r < B2) {
                    tree = (r >= B) ? 1 : 0;
                    const int j = lo + r - tree * B;
                    const int* ch = (tree ? P.rch : P.lch) + 4 * j;
                    c0 = ch[0]; c1 = ch[1]; c2 = ch[2]; c3 = ch[3];
                }
                const u16* hb = P.hbf + (size_t)tree * 513 * 512;
                hpA[Mi][0] = hb + (size_t)c0 * 512; hpA[Mi][1] = hb + (size_t)c1 * 512;
                hpA[Mi][2] = hb + (size_t)c2 * 512; hpA[Mi][3] = hb + (size_t)c3 * 512;
            }
            const u16* fpA[8];
#pragma unroll
            for (int Ft = 0; Ft < 8; ++Ft) {
                const int fr = Ft * 16 + m;
                const int r = rg * 32 + (fr >> 2), s = fr & 3;
                int tree = 0, c = 512;
                if (r < B2) {
                    tree = (r >= B) ? 1 : 0;
                    const int j = lo + r - tree * B;
                    c = ((tree ? P.rch : P.lch) + 4 * j)[s];
                }
                fpA[Ft] = P.hbf + ((size_t)tree * 513 + c) * 512;
            }
            const u16* pBi[3][2]; const u16* pBf[2];
#pragma unroll
            for (int g = 0; g < 3; ++g)
#pragma unroll
                for (int Nj = 0; Nj < 2; ++Nj)
                    pBi[g][Nj] = P.WiouhT + (size_t)(g * 512 + colbase + Nj * 16 + m) * 512;
#pragma unroll
            for (int Nj = 0; Nj < 2; ++Nj)
                pBf[Nj] = P.WfhT + (size_t)(colbase + Nj * 16 + m) * 512;

            f32x4 aci[3][2][2];
            f32x4 acf[8][2];
#pragma unroll
            for (int g = 0; g < 3; ++g)
#pragma unroll
                for (int Mi = 0; Mi < 2; ++Mi)
#pragma unroll
                    for (int Nj = 0; Nj < 2; ++Nj) aci[g][Mi][Nj] = (f32x4){0.f, 0.f, 0.f, 0.f};
#pragma unroll
            for (int Ft = 0; Ft < 8; ++Ft)
#pragma unroll
                for (int Nj = 0; Nj < 2; ++Nj) acf[Ft][Nj] = (f32x4){0.f, 0.f, 0.f, 0.f};

#pragma unroll 1
            for (int k0 = 0; k0 < 512; k0 += 32) {
                const int koff = k0 + q * 8;
                bf16x8 ah[2];
#pragma unroll
                for (int Mi = 0; Mi < 2; ++Mi) {
                    float s0[8] = {0.f, 0.f, 0.f, 0.f, 0.f, 0.f, 0.f, 0.f};
#pragma unroll
                    for (int s = 0; s < 4; ++s) {
                        bf16x8 v = *(const bf16x8*)(hpA[Mi][s] + koff);
#pragma unroll
                        for (int t = 0; t < 8; ++t) s0[t] += (float)v[t];
                    }
                    bf16x8 a;
#pragma unroll
                    for (int t = 0; t < 8; ++t) a[t] = (__bf16)s0[t];
                    ah[Mi] = a;
                }
                bf16x8 af[8];
#pragma unroll
                for (int Ft = 0; Ft < 8; ++Ft) af[Ft] = *(const bf16x8*)(fpA[Ft] + koff);
#pragma unroll
                for (int Nj = 0; Nj < 2; ++Nj) {
#pragma unroll
                    for (int g = 0; g < 3; ++g) {
                        bf16x8 b = *(const bf16x8*)(pBi[g][Nj] + koff);
                        aci[g][0][Nj] = mfma16(ah[0], b, aci[g][0][Nj]);
                        aci[g][1][Nj] = mfma16(ah[1], b, aci[g][1][Nj]);
                    }
                    bf16x8 b2 = *(const bf16x8*)(pBf[Nj] + koff);
#pragma unroll
                    for (int Ft = 0; Ft < 8; ++Ft) acf[Ft][Nj] = mfma16(af[Ft], b2, acf[Ft][Nj]);
                }
            }

            // f epilogue: lane (q,m) owns node R=4*Ft+q, child=reg, col=Nj*16+m
#pragma unroll
            for (int Ft = 0; Ft < 8; ++Ft) {
                const int R = 4 * Ft + q;
                const int r = rg * 32 + R;
                int tree = 0, j = lo, cc0 = 512, cc1 = 512, cc2 = 512, cc3 = 512;
                if (r < B2) {
                    tree = (r >= B) ? 1 : 0;
                    j = lo + r - tree * B;
                    const int* ch = (tree ? P.rch : P.lch) + 4 * j;
                    cc0 = ch[0]; cc1 = ch[1]; cc2 = ch[2]; cc3 = ch[3];
                }
                const float* cb = P.cbuf + (size_t)tree * 513 * 512;
#pragma unroll
                for (int Nj = 0; Nj < 2; ++Nj) {
                    const int C = colbase + Nj * 16 + m;
                    const float xf = bf2f(P.xcat[(size_t)(tree * 512 + j) * 2048 + 1536 + C]);
                    const float bfh = P.b_fh[C] + xf;
                    float fs = sigm(acf[Ft][Nj][0] + bfh) * cb[(size_t)cc0 * 512 + C]
                             + sigm(acf[Ft][Nj][1] + bfh) * cb[(size_t)cc1 * 512 + C]
                             + sigm(acf[Ft][Nj][2] + bfh) * cb[(size_t)cc2 * 512 + C]
                             + sigm(acf[Ft][Nj][3] + bfh) * cb[(size_t)cc3 * 512 + C];
                    smem[w][R][Nj * 16 + m] = fs;
                }
            }
            __syncthreads();
            // gating epilogue: lane (q,m), row R = Mi*16+q*4+rr
#pragma unroll
            for (int Mi = 0; Mi < 2; ++Mi)
#pragma unroll
                for (int rr = 0; rr < 4; ++rr) {
                    const int R = Mi * 16 + q * 4 + rr;
                    const int r = rg * 32 + R;
                    if (r >= B2) continue;
                    const int tree = (r >= B) ? 1 : 0;
                    const int j = lo + r - tree * B;
                    const size_t xrow = (size_t)(tree * 512 + j) * 2048;
#pragma unroll
                    for (int Nj = 0; Nj < 2; ++Nj) {
                        const int C = colbase + Nj * 16 + m;
                        const float ii = aci[0][Mi][Nj][rr] + P.b_iouh[C]        + bf2f(P.xcat[xrow + C]);
                        const float oo = aci[1][Mi][Nj][rr] + P.b_iouh[512 + C]  + bf2f(P.xcat[xrow + 512 + C]);
                        const float uu = aci[2][Mi][Nj][rr] + P.b_iouh[1024 + C] + bf2f(P.xcat[xrow + 1024 + C]);
                        const float ig = sigm(ii), og = sigm(oo), ug = tanhf(uu);
                        const float cv = ig * ug + smem[w][R][Nj * 16 + m];
                        P.cbuf[((size_t)tree * 513 + j) * 512 + C] = cv;
                        P.hbf[((size_t)tree * 513 + j) * 512 + C] = f2bf(og * tanhf(cv));
                    }
                }
        }
        gridbar(P.bar, tgt += NB);
    }

    // ================= head1: hid_raw[col] += vec @ Wh ======================
    if (bb < 64) {
        const float* lc = P.cbuf + (size_t)511 * 512;
        const float* rc = P.cbuf + (size_t)(513 + 511) * 512;
        const int cg8 = bb & 7, kg = bb >> 3;
        const int col = cg8 * 64 + lane;
        const int kbase = kg * 128 + w * 32;
        float acc = 0.f;
#pragma unroll 8
        for (int i = 0; i < 32; ++i) {
            const int k = kbase + i;
            float v;
            if (k < 512) v = lc[k] * rc[k];
            else { const int kk = k - 512; v = fabsf(lc[kk] - rc[kk]); }
            acc += v * P.Wh[(size_t)k * 512 + col];
        }
        smem[w][0][lane] = acc;
        __syncthreads();
        if (w == 0)
            atomicAdd(&P.hid_raw[col],
                      smem[0][0][lane] + smem[1][0][lane] + smem[2][0][lane] + smem[3][0][lane]);
    }
    gridbar(P.bar, tgt += NB);

    // ================= head2: log_softmax(sigm(hid)@Wp + bp) ================
    if (bb == 0) {
        float a[5] = {0.f, 0.f, 0.f, 0.f, 0.f};
        for (int k = tid; k < 512; k += 256) {
            const float hv = sigm(P.hid_raw[k] + P.bh[k]);
#pragma unroll
            for (int cc = 0; cc < 5; ++cc) a[cc] += hv * P.Wp[(size_t)k * 5 + cc];
        }
#pragma unroll
        for (int cc = 0; cc < 5; ++cc)
            for (int off = 32; off; off >>= 1) a[cc] += __shfl_xor(a[cc], off, 64);
        if (lane == 0)
#pragma unroll
            for (int cc = 0; cc < 5; ++cc) smem[w][1][cc] = a[cc];
        __syncthreads();
        if (tid == 0) {
            float lg[5], mx = -1e30f;
#pragma unroll
            for (int cc = 0; cc < 5; ++cc) {
                lg[cc] = smem[0][1][cc] + smem[1][1][cc] + smem[2][1][cc] + smem[3][1][cc] + P.bp[cc];
                mx = fmaxf(mx, lg[cc]);
            }
            float s = 0.f;
#pragma unroll
            for (int cc = 0; cc < 5; ++cc) s += __expf(lg[cc] - mx);
            const float lse = mx + __logf(s);
#pragma unroll
            for (int cc = 0; cc < 5; ++cc) P.out[cc] = lg[cc] - lse;
        }
    }
}

// ---------------- launch ----------------------------------------------------
extern "C" void kernel_launch(void* const* d_in, const int* in_sizes, int n_in,
                              void* d_out, int out_size, void* d_ws, size_t ws_size,
                              hipStream_t stream)
{
    Params P;
    P.lin    = (const int*)d_in[0];
    P.rin    = (const int*)d_in[1];
    P.lch    = (const int*)d_in[2];
    P.rch    = (const int*)d_in[3];
    P.emb    = (const float*)d_in[4];
    P.W_ioux = (const float*)d_in[5];
    P.b_ioux = (const float*)d_in[6];
    P.W_iouh = (const float*)d_in[7];
    P.b_iouh = (const float*)d_in[8];
    P.W_fx   = (const float*)d_in[9];
    P.b_fx   = (const float*)d_in[10];
    P.W_fh   = (const float*)d_in[11];
    P.b_fh   = (const float*)d_in[12];
    P.Wh     = (const float*)d_in[13];
    P.bh     = (const float*)d_in[14];
    P.Wp     = (const float*)d_in[15];
    P.bp     = (const float*)d_in[16];
    P.out    = (float*)d_out;
    (void)ws_size; (void)n_in; (void)in_sizes; (void)out_size;

    char* p = (char*)d_ws;
    P.WiouhT  = (u16*)p;   p += (size_t)1536 * 512 * 2;
    P.WfhT    = (u16*)p;   p += (size_t)512 * 512 * 2;
    P.WxT     = (u16*)p;   p += (size_t)2048 * 512 * 2;
    P.xcat    = (u16*)p;   p += (size_t)1024 * 2048 * 2;
    P.hbf     = (u16*)p;   p += (size_t)2 * 513 * 512 * 2;
    P.cbuf    = (float*)p; p += (size_t)2 * 513 * 512 * 4;
    P.hid_raw = (float*)p; p += (size_t)512 * 4;
    P.bar     = (unsigned*)p; p += 64;

    hipMemsetAsync(P.bar, 0, sizeof(unsigned), stream);
    fused<<<NB, 256, 0, stream>>>(P);
}

// Round 6
// 569.648 us; speedup vs baseline: 4.0282x; 1.0356x over previous
//
#include <hip/hip_runtime.h>
#include <hip/hip_bf16.h>
#include <math.h>

// SimilarityTreeLSTM on MI355X — round 6: fused kernel, fence-free barriers.
//
// R5 post-mortem: ~46 us/barrier = agent release/acquire fences (buffer_wbl2
// sc1 + buffer_inv sc1 full-L2 tag walks, 256 blocks, 32 serialized per XCD,
// x9 barriers) dominated the 443 us dispatch (compute is ~25 us: MfmaUtil
// 0.55%, VALUBusy 2.2%). Fix: no cache maintenance per barrier at all.
//  - All cross-block state writes use relaxed AGENT-scope stores
//    (__hip_atomic_store -> sc-flagged store, lands at coherence point).
//  - Readers use normal cached loads: every state row is written once and
//    first read only after its write (rows cacheline-aligned, never
//    re-written), so no reader cache can hold a stale copy of our data.
//  - Pre-existing 0xAA poison copies (harness fill populates L2s) are
//    discarded by ONE acquire-agent fence per block at kernel entry.
//  - Barrier: syncthreads (vmcnt drain) + relaxed agent add/spin +
//    workgroup-scope fences (compiler/waitcnt only, no cache ops).
//
// Levels (j = 511-i, complete 4-ary heap):
//   ph0 [0,171) ph1 [171,427) ph2 [427,491) ph3 [491,507) ph4 [507,511) ph5 [511,512)
// Pad child index 512 -> per-tree zero row; state buffers [2][513][512].

typedef __attribute__((ext_vector_type(8))) __bf16 bf16x8;
typedef __attribute__((ext_vector_type(4))) float f32x4;
typedef unsigned short u16;

#define NB 256

struct Params {
    const int *lin, *rin, *lch, *rch;
    const float *emb, *W_ioux, *b_ioux, *W_iouh, *b_iouh;
    const float *W_fx, *b_fx, *W_fh, *b_fh, *Wh, *bh, *Wp, *bp;
    float* out;
    u16 *WiouhT, *WfhT, *WxT, *xcat, *hbf;
    float *cbuf, *hid_raw;
    unsigned* bar;
};

__device__ __forceinline__ float sigm(float x) { return 1.0f / (1.0f + __expf(-x)); }
__device__ __forceinline__ u16 f2bf(float f) {
    union { float f; unsigned int u; } v; v.f = f;
    unsigned int r = v.u + 0x7FFF + ((v.u >> 16) & 1);
    return (u16)(r >> 16);
}
__device__ __forceinline__ float bf2f(u16 b) {
    union { unsigned int u; float f; } v; v.u = ((unsigned int)b) << 16;
    return v.f;
}
__device__ __forceinline__ f32x4 mfma16(bf16x8 a, bf16x8 b, f32x4 c) {
    return __builtin_amdgcn_mfma_f32_16x16x32_bf16(a, b, c, 0, 0, 0);
}
__device__ __forceinline__ bf16x8 load_f32_as_bf8(const float* p) {
    float4 x = *(const float4*)p;
    float4 y = *(const float4*)(p + 4);
    bf16x8 r;
    r[0] = (__bf16)x.x; r[1] = (__bf16)x.y; r[2] = (__bf16)x.z; r[3] = (__bf16)x.w;
    r[4] = (__bf16)y.x; r[5] = (__bf16)y.y; r[6] = (__bf16)y.z; r[7] = (__bf16)y.w;
    return r;
}
// Cross-block-visible stores: relaxed agent scope -> coherence point, no fence.
__device__ __forceinline__ void stg16(u16* p, u16 v) {
    __hip_atomic_store(p, v, __ATOMIC_RELAXED, __HIP_MEMORY_SCOPE_AGENT);
}
__device__ __forceinline__ void stg32(float* p, float v) {
    __hip_atomic_store(p, v, __ATOMIC_RELAXED, __HIP_MEMORY_SCOPE_AGENT);
}

// Grid barrier: NO cache maintenance. syncthreads drains vmcnt (agent stores
// are at the coherence point before tid0 signals); workgroup fences are
// compiler/waitcnt-only.
__device__ __forceinline__ void gridbar(unsigned* bar, unsigned target)
{
    __builtin_amdgcn_fence(__ATOMIC_RELEASE, "workgroup");
    __syncthreads();
    if (threadIdx.x == 0) {
        __hip_atomic_fetch_add(bar, 1u, __ATOMIC_RELAXED, __HIP_MEMORY_SCOPE_AGENT);
        while (__hip_atomic_load(bar, __ATOMIC_RELAXED, __HIP_MEMORY_SCOPE_AGENT) < target)
            __builtin_amdgcn_s_sleep(4);
    }
    __syncthreads();
    __builtin_amdgcn_fence(__ATOMIC_ACQUIRE, "workgroup");
}

__global__ __launch_bounds__(256)
void fused(Params P)
{
    __shared__ float smem[4][32][33];
    const int bb = blockIdx.x, tid = threadIdx.x;
    const int w = tid >> 6, lane = tid & 63, m = lane & 15, q = lane >> 4;
    unsigned tgt = 0;

    // One-time: discard any stale (poison) copies of workspace lines in this
    // CU's L1 / XCD's L2 before any normal load of workspace data.
    if (tid < 64) __builtin_amdgcn_fence(__ATOMIC_ACQUIRE, "agent");
    __syncthreads();

    // ================= S0: weight transpose/convert + zero init ============
    {
        const int tx = tid & 31, ty = tid >> 5;
#pragma unroll 1
        for (int u = 0; u < 8; ++u) {
            const int tt = bb * 8 + u;
            const float* src; u16* dst; int lds_, k0, n0;
            if (tt < 768)       { src = P.W_ioux; lds_ = 1536; dst = P.WxT;
                                  k0 = (tt & 15) * 32; n0 = (tt >> 4) * 32; }
            else if (tt < 1024) { const int t2 = tt - 768; src = P.W_fx; lds_ = 512;
                                  dst = P.WxT + (size_t)1536 * 512;
                                  k0 = (t2 & 15) * 32; n0 = (t2 >> 4) * 32; }
            else if (tt < 1792) { const int t2 = tt - 1024; src = P.W_iouh; lds_ = 1536;
                                  dst = P.WiouhT; k0 = (t2 & 15) * 32; n0 = (t2 >> 4) * 32; }
            else                { const int t2 = tt - 1792; src = P.W_fh; lds_ = 512;
                                  dst = P.WfhT; k0 = (t2 & 15) * 32; n0 = (t2 >> 4) * 32; }
            __syncthreads();
#pragma unroll
            for (int i = 0; i < 4; ++i)
                smem[0][ty + 8 * i][tx] = src[(size_t)(k0 + ty + 8 * i) * lds_ + n0 + tx];
            __syncthreads();
#pragma unroll
            for (int i = 0; i < 4; ++i)
                stg16(&dst[(size_t)(n0 + ty + 8 * i) * 512 + k0 + tx], f2bf(smem[0][tx][ty + 8 * i]));
        }
        if (bb == 0) {
            for (int i = tid; i < 512; i += 256) {
                stg16(&P.hbf[(size_t)512 * 512 + i], (u16)0);
                stg16(&P.hbf[(size_t)1025 * 512 + i], (u16)0);
                stg32(&P.cbuf[(size_t)512 * 512 + i], 0.f);
                stg32(&P.cbuf[(size_t)1025 * 512 + i], 0.f);
                stg32(&P.hid_raw[i], 0.f);
            }
        }
    }
    gridbar(P.bar, tgt += NB);

    // ================= S1: prege — xcat[1024][2048] = bf16(emb[tok])@WxT^T + b
    {
        const int mt = bb & 31, nb = bb >> 5;
        const int colbase = nb * 256 + w * 64;
        const int r0 = mt * 32 + m, r1 = r0 + 16;
        const int tok0 = (r0 < 512) ? P.lin[r0] : P.rin[r0 - 512];
        const int tok1 = (r1 < 512) ? P.lin[r1] : P.rin[r1 - 512];
        const float* A0 = P.emb + (size_t)tok0 * 512;
        const float* A1 = P.emb + (size_t)tok1 * 512;
        f32x4 acc[2][4];
#pragma unroll
        for (int i = 0; i < 2; ++i)
#pragma unroll
            for (int j = 0; j < 4; ++j) acc[i][j] = (f32x4){0.f, 0.f, 0.f, 0.f};
        for (int k0 = 0; k0 < 512; k0 += 32) {
            const int koff = k0 + q * 8;
            bf16x8 a0 = load_f32_as_bf8(A0 + koff);
            bf16x8 a1 = load_f32_as_bf8(A1 + koff);
#pragma unroll
            for (int jj = 0; jj < 4; ++jj) {
                bf16x8 b = *(const bf16x8*)(P.WxT + (size_t)(colbase + jj * 16 + m) * 512 + koff);
                acc[0][jj] = mfma16(a0, b, acc[0][jj]);
                acc[1][jj] = mfma16(a1, b, acc[1][jj]);
            }
        }
#pragma unroll
        for (int i = 0; i < 2; ++i)
#pragma unroll
            for (int jj = 0; jj < 4; ++jj)
#pragma unroll
                for (int rr = 0; rr < 4; ++rr) {
                    const int R = mt * 32 + i * 16 + q * 4 + rr;
                    const int col = colbase + jj * 16 + m;
                    const float bias = (col < 1536) ? P.b_ioux[col] : P.b_fx[col - 1536];
                    stg16(&P.xcat[(size_t)R * 2048 + col], f2bf(acc[i][jj][rr] + bias));
                }
    }
    gridbar(P.bar, tgt += NB);

    // ================= phases 0..5: fused gather + dual GEMM + gating ======
    constexpr int los[6] = {0, 171, 427, 491, 507, 511};
    constexpr int Bsz[6] = {171, 256, 64, 16, 4, 1};
#pragma unroll 1
    for (int ph = 0; ph < 6; ++ph) {
        const int lo = los[ph], B = Bsz[ph], B2 = 2 * B;
        const int RG = (B2 + 31) >> 5;
        if (bb < RG * 4) {
            const int rg = bb >> 2, cgp = bb & 3;
            const int colbase = cgp * 128 + w * 32;

            const u16* hpA[2][4];
#pragma unroll
            for (int Mi = 0; Mi < 2; ++Mi) {
                const int r = rg * 32 + Mi * 16 + m;
                int tree = 0, c0 = 512, c1 = 512, c2 = 512, c3 = 512;
                if (r < B2) {
                    tree = (r >= B) ? 1 : 0;
                    const int j = lo + r - tree * B;
                    const int* ch = (tree ? P.rch : P.lch) + 4 * j;
                    c0 = ch[0]; c1 = ch[1]; c2 = ch[2]; c3 = ch[3];
                }
                const u16* hb = P.hbf + (size_t)tree * 513 * 512;
                hpA[Mi][0] = hb + (size_t)c0 * 512; hpA[Mi][1] = hb + (size_t)c1 * 512;
                hpA[Mi][2] = hb + (size_t)c2 * 512; hpA[Mi][3] = hb + (size_t)c3 * 512;
            }
            const u16* fpA[8];
#pragma unroll
            for (int Ft = 0; Ft < 8; ++Ft) {
                const int fr = Ft * 16 + m;
                const int r = rg * 32 + (fr >> 2), s = fr & 3;
                int tree = 0, c = 512;
                if (r < B2) {
                    tree = (r >= B) ? 1 : 0;
                    const int j = lo + r - tree * B;
                    c = ((tree ? P.rch : P.lch) + 4 * j)[s];
                }
                fpA[Ft] = P.hbf + ((size_t)tree * 513 + c) * 512;
            }
            const u16* pBi[3][2]; const u16* pBf[2];
#pragma unroll
            for (int g = 0; g < 3; ++g)
#pragma unroll
                for (int Nj = 0; Nj < 2; ++Nj)
                    pBi[g][Nj] = P.WiouhT + (size_t)(g * 512 + colbase + Nj * 16 + m) * 512;
#pragma unroll
            for (int Nj = 0; Nj < 2; ++Nj)
                pBf[Nj] = P.WfhT + (size_t)(colbase + Nj * 16 + m) * 512;

            f32x4 aci[3][2][2];
            f32x4 acf[8][2];
#pragma unroll
            for (int g = 0; g < 3; ++g)
#pragma unroll
                for (int Mi = 0; Mi < 2; ++Mi)
#pragma unroll
                    for (int Nj = 0; Nj < 2; ++Nj) aci[g][Mi][Nj] = (f32x4){0.f, 0.f, 0.f, 0.f};
#pragma unroll
            for (int Ft = 0; Ft < 8; ++Ft)
#pragma unroll
                for (int Nj = 0; Nj < 2; ++Nj) acf[Ft][Nj] = (f32x4){0.f, 0.f, 0.f, 0.f};

#pragma unroll 1
            for (int k0 = 0; k0 < 512; k0 += 32) {
                const int koff = k0 + q * 8;
                bf16x8 ah[2];
#pragma unroll
                for (int Mi = 0; Mi < 2; ++Mi) {
                    float s0[8] = {0.f, 0.f, 0.f, 0.f, 0.f, 0.f, 0.f, 0.f};
#pragma unroll
                    for (int s = 0; s < 4; ++s) {
                        bf16x8 v = *(const bf16x8*)(hpA[Mi][s] + koff);
#pragma unroll
                        for (int t = 0; t < 8; ++t) s0[t] += (float)v[t];
                    }
                    bf16x8 a;
#pragma unroll
                    for (int t = 0; t < 8; ++t) a[t] = (__bf16)s0[t];
                    ah[Mi] = a;
                }
                bf16x8 af[8];
#pragma unroll
                for (int Ft = 0; Ft < 8; ++Ft) af[Ft] = *(const bf16x8*)(fpA[Ft] + koff);
#pragma unroll
                for (int Nj = 0; Nj < 2; ++Nj) {
#pragma unroll
                    for (int g = 0; g < 3; ++g) {
                        bf16x8 b = *(const bf16x8*)(pBi[g][Nj] + koff);
                        aci[g][0][Nj] = mfma16(ah[0], b, aci[g][0][Nj]);
                        aci[g][1][Nj] = mfma16(ah[1], b, aci[g][1][Nj]);
                    }
                    bf16x8 b2 = *(const bf16x8*)(pBf[Nj] + koff);
#pragma unroll
                    for (int Ft = 0; Ft < 8; ++Ft) acf[Ft][Nj] = mfma16(af[Ft], b2, acf[Ft][Nj]);
                }
            }

            // f epilogue: lane (q,m) owns node R=4*Ft+q, child=reg, col=Nj*16+m
#pragma unroll
            for (int Ft = 0; Ft < 8; ++Ft) {
                const int R = 4 * Ft + q;
                const int r = rg * 32 + R;
                int tree = 0, j = lo, cc0 = 512, cc1 = 512, cc2 = 512, cc3 = 512;
                if (r < B2) {
                    tree = (r >= B) ? 1 : 0;
                    j = lo + r - tree * B;
                    const int* ch = (tree ? P.rch : P.lch) + 4 * j;
                    cc0 = ch[0]; cc1 = ch[1]; cc2 = ch[2]; cc3 = ch[3];
                }
                const float* cb = P.cbuf + (size_t)tree * 513 * 512;
#pragma unroll
                for (int Nj = 0; Nj < 2; ++Nj) {
                    const int C = colbase + Nj * 16 + m;
                    const float xf = bf2f(P.xcat[(size_t)(tree * 512 + j) * 2048 + 1536 + C]);
                    const float bfh = P.b_fh[C] + xf;
                    float fs = sigm(acf[Ft][Nj][0] + bfh) * cb[(size_t)cc0 * 512 + C]
                             + sigm(acf[Ft][Nj][1] + bfh) * cb[(size_t)cc1 * 512 + C]
                             + sigm(acf[Ft][Nj][2] + bfh) * cb[(size_t)cc2 * 512 + C]
                             + sigm(acf[Ft][Nj][3] + bfh) * cb[(size_t)cc3 * 512 + C];
                    smem[w][R][Nj * 16 + m] = fs;
                }
            }
            __syncthreads();
            // gating epilogue: lane (q,m), row R = Mi*16+q*4+rr
#pragma unroll
            for (int Mi = 0; Mi < 2; ++Mi)
#pragma unroll
                for (int rr = 0; rr < 4; ++rr) {
                    const int R = Mi * 16 + q * 4 + rr;
                    const int r = rg * 32 + R;
                    if (r >= B2) continue;
                    const int tree = (r >= B) ? 1 : 0;
                    const int j = lo + r - tree * B;
                    const size_t xrow = (size_t)(tree * 512 + j) * 2048;
#pragma unroll
                    for (int Nj = 0; Nj < 2; ++Nj) {
                        const int C = colbase + Nj * 16 + m;
                        const float ii = aci[0][Mi][Nj][rr] + P.b_iouh[C]        + bf2f(P.xcat[xrow + C]);
                        const float oo = aci[1][Mi][Nj][rr] + P.b_iouh[512 + C]  + bf2f(P.xcat[xrow + 512 + C]);
                        const float uu = aci[2][Mi][Nj][rr] + P.b_iouh[1024 + C] + bf2f(P.xcat[xrow + 1024 + C]);
                        const float ig = sigm(ii), og = sigm(oo), ug = tanhf(uu);
                        const float cv = ig * ug + smem[w][R][Nj * 16 + m];
                        stg32(&P.cbuf[((size_t)tree * 513 + j) * 512 + C], cv);
                        stg16(&P.hbf[((size_t)tree * 513 + j) * 512 + C], f2bf(og * tanhf(cv)));
                    }
                }
        }
        gridbar(P.bar, tgt += NB);
    }

    // ================= head1: hid_raw[col] += vec @ Wh ======================
    if (bb < 64) {
        const float* lc = P.cbuf + (size_t)511 * 512;
        const float* rc = P.cbuf + (size_t)(513 + 511) * 512;
        const int cg8 = bb & 7, kg = bb >> 3;
        const int col = cg8 * 64 + lane;
        const int kbase = kg * 128 + w * 32;
        float acc = 0.f;
#pragma unroll 8
        for (int i = 0; i < 32; ++i) {
            const int k = kbase + i;
            float v;
            if (k < 512) v = lc[k] * rc[k];
            else { const int kk = k - 512; v = fabsf(lc[kk] - rc[kk]); }
            acc += v * P.Wh[(size_t)k * 512 + col];
        }
        smem[w][0][lane] = acc;
        __syncthreads();
        if (w == 0)
            __hip_atomic_fetch_add(&P.hid_raw[col],
                smem[0][0][lane] + smem[1][0][lane] + smem[2][0][lane] + smem[3][0][lane],
                __ATOMIC_RELAXED, __HIP_MEMORY_SCOPE_AGENT);
    }
    gridbar(P.bar, tgt += NB);

    // ================= head2: log_softmax(sigm(hid)@Wp + bp) ================
    if (bb == 0) {
        float a[5] = {0.f, 0.f, 0.f, 0.f, 0.f};
        for (int k = tid; k < 512; k += 256) {
            const float hv = sigm(P.hid_raw[k] + P.bh[k]);
#pragma unroll
            for (int cc = 0; cc < 5; ++cc) a[cc] += hv * P.Wp[(size_t)k * 5 + cc];
        }
#pragma unroll
        for (int cc = 0; cc < 5; ++cc)
            for (int off = 32; off; off >>= 1) a[cc] += __shfl_xor(a[cc], off, 64);
        if (lane == 0)
#pragma unroll
            for (int cc = 0; cc < 5; ++cc) smem[w][1][cc] = a[cc];
        __syncthreads();
        if (tid == 0) {
            float lg[5], mx = -1e30f;
#pragma unroll
            for (int cc = 0; cc < 5; ++cc) {
                lg[cc] = smem[0][1][cc] + smem[1][1][cc] + smem[2][1][cc] + smem[3][1][cc] + P.bp[cc];
                mx = fmaxf(mx, lg[cc]);
            }
            float s = 0.f;
#pragma unroll
            for (int cc = 0; cc < 5; ++cc) s += __expf(lg[cc] - mx);
            const float lse = mx + __logf(s);
#pragma unroll
            for (int cc = 0; cc < 5; ++cc) P.out[cc] = lg[cc] - lse;
        }
    }
}

// ---------------- launch ----------------------------------------------------
extern "C" void kernel_launch(void* const* d_in, const int* in_sizes, int n_in,
                              void* d_out, int out_size, void* d_ws, size_t ws_size,
                              hipStream_t stream)
{
    Params P;
    P.lin    = (const int*)d_in[0];
    P.rin    = (const int*)d_in[1];
    P.lch    = (const int*)d_in[2];
    P.rch    = (const int*)d_in[3];
    P.emb    = (const float*)d_in[4];
    P.W_ioux = (const float*)d_in[5];
    P.b_ioux = (const float*)d_in[6];
    P.W_iouh = (const float*)d_in[7];
    P.b_iouh = (const float*)d_in[8];
    P.W_fx   = (const float*)d_in[9];
    P.b_fx   = (const float*)d_in[10];
    P.W_fh   = (const float*)d_in[11];
    P.b_fh   = (const float*)d_in[12];
    P.Wh     = (const float*)d_in[13];
    P.bh     = (const float*)d_in[14];
    P.Wp     = (const float*)d_in[15];
    P.bp     = (const float*)d_in[16];
    P.out    = (float*)d_out;
    (void)ws_size; (void)n_in; (void)in_sizes; (void)out_size;

    char* p = (char*)d_ws;
    P.WiouhT  = (u16*)p;   p += (size_t)1536 * 512 * 2;
    P.WfhT    = (u16*)p;   p += (size_t)512 * 512 * 2;
    P.WxT     = (u16*)p;   p += (size_t)2048 * 512 * 2;
    P.xcat    = (u16*)p;   p += (size_t)1024 * 2048 * 2;
    P.hbf     = (u16*)p;   p += (size_t)2 * 513 * 512 * 2;
    P.cbuf    = (float*)p; p += (size_t)2 * 513 * 512 * 4;
    P.hid_raw = (float*)p; p += (size_t)512 * 4;
    P.bar     = (unsigned*)p; p += 64;

    hipMemsetAsync(P.bar, 0, sizeof(unsigned), stream);
    fused<<<NB, 256, 0, stream>>>(P);
}

// Round 7
// 557.315 us; speedup vs baseline: 4.1173x; 1.0221x over previous
//
#include <hip/hip_runtime.h>
#include <hip/hip_bf16.h>
#include <math.h>

// SimilarityTreeLSTM on MI355X — round 7: hierarchical grid barrier +
// early block retirement. Compute identical to round 6.
//
// R6 post-mortem: removing all per-barrier cache fences changed nothing
// (443->469 us, FETCH identical) -> fences exonerated. New theory: ~45 us
// per barrier interval = same-cacheline RMW serialization at the coherence
// point (256 fetch_adds on ONE line, ~100-200 cyc each cross-XCD) plus 256
// uncached pollers queueing on that same line. Fix:
//  - two-level barrier: 8 leaf lines (32 RMWs each, parallel) + root line
//    (8 leader RMWs); waiters poll root only.
//  - blocks 64..255 are never needed after S1 (max phase parallelism = 64
//    blocks, head1 = 64): they arrive at barrier 2 and EXIT. Later barriers
//    have 64 participants, 2 root RMWs.
//
// Levels (j = 511-i, complete 4-ary heap):
//   ph0 [0,171) ph1 [171,427) ph2 [427,491) ph3 [491,507) ph4 [507,511) ph5 [511,512)
// Pad child index 512 -> per-tree zero row; state buffers [2][513][512].

typedef __attribute__((ext_vector_type(8))) __bf16 bf16x8;
typedef __attribute__((ext_vector_type(4))) float f32x4;
typedef unsigned short u16;

#define NB 256

struct Params {
    const int *lin, *rin, *lch, *rch;
    const float *emb, *W_ioux, *b_ioux, *W_iouh, *b_iouh;
    const float *W_fx, *b_fx, *W_fh, *b_fh, *Wh, *bh, *Wp, *bp;
    float* out;
    u16 *WiouhT, *WfhT, *WxT, *xcat, *hbf;
    float *cbuf, *hid_raw;
    unsigned* bar;   // [0]=root, [16+g*16]=leaf g (64B-separated lines)
};

__device__ __forceinline__ float sigm(float x) { return 1.0f / (1.0f + __expf(-x)); }
__device__ __forceinline__ u16 f2bf(float f) {
    union { float f; unsigned int u; } v; v.f = f;
    unsigned int r = v.u + 0x7FFF + ((v.u >> 16) & 1);
    return (u16)(r >> 16);
}
__device__ __forceinline__ float bf2f(u16 b) {
    union { unsigned int u; float f; } v; v.u = ((unsigned int)b) << 16;
    return v.f;
}
__device__ __forceinline__ f32x4 mfma16(bf16x8 a, bf16x8 b, f32x4 c) {
    return __builtin_amdgcn_mfma_f32_16x16x32_bf16(a, b, c, 0, 0, 0);
}
__device__ __forceinline__ bf16x8 load_f32_as_bf8(const float* p) {
    float4 x = *(const float4*)p;
    float4 y = *(const float4*)(p + 4);
    bf16x8 r;
    r[0] = (__bf16)x.x; r[1] = (__bf16)x.y; r[2] = (__bf16)x.z; r[3] = (__bf16)x.w;
    r[4] = (__bf16)y.x; r[5] = (__bf16)y.y; r[6] = (__bf16)y.z; r[7] = (__bf16)y.w;
    return r;
}
__device__ __forceinline__ void stg16(u16* p, u16 v) {
    __hip_atomic_store(p, v, __ATOMIC_RELAXED, __HIP_MEMORY_SCOPE_AGENT);
}
__device__ __forceinline__ void stg32(float* p, float v) {
    __hip_atomic_store(p, v, __ATOMIC_RELAXED, __HIP_MEMORY_SCOPE_AGENT);
}
__device__ __forceinline__ unsigned ald(unsigned* p) {
    return __hip_atomic_load(p, __ATOMIC_RELAXED, __HIP_MEMORY_SCOPE_AGENT);
}
__device__ __forceinline__ void aadd(unsigned* p) {
    __hip_atomic_fetch_add(p, 1u, __ATOMIC_RELAXED, __HIP_MEMORY_SCOPE_AGENT);
}

// Arrive at barrier: all waves' stores drained (syncthreads), tid0 bumps leaf.
__device__ __forceinline__ void bar_arrive(unsigned* leaf) {
    __builtin_amdgcn_fence(__ATOMIC_RELEASE, "workgroup");
    __syncthreads();
    if (threadIdx.x == 0) aadd(leaf);
}
// Leader promotes leaf->root; everyone waits on root.
__device__ __forceinline__ void bar_wait(unsigned* root, unsigned* leaf,
                                         unsigned leaf_tgt, unsigned root_tgt,
                                         bool leader) {
    if (threadIdx.x == 0) {
        if (leader) {
            while (ald(leaf) < leaf_tgt) __builtin_amdgcn_s_sleep(1);
            aadd(root);
        }
        while (ald(root) < root_tgt) __builtin_amdgcn_s_sleep(1);
    }
    __syncthreads();
    __builtin_amdgcn_fence(__ATOMIC_ACQUIRE, "workgroup");
}

__global__ __launch_bounds__(256)
void fused(Params P)
{
    __shared__ float smem[4][32][33];
    const int bb = blockIdx.x, tid = threadIdx.x;
    const int w = tid >> 6, lane = tid & 63, m = lane & 15, q = lane >> 4;
    const int grp = bb >> 5;
    const bool leader = (bb & 31) == 0;
    unsigned* root = P.bar;
    unsigned* leaf = P.bar + 16 + grp * 16;

    // One-time: discard stale poison copies in this CU's L1 / XCD L2 before
    // any normal cached load of workspace data.
    if (tid < 64) __builtin_amdgcn_fence(__ATOMIC_ACQUIRE, "agent");
    __syncthreads();

    // ================= S0: weight transpose/convert + zero init ============
    {
        const int tx = tid & 31, ty = tid >> 5;
#pragma unroll 1
        for (int u = 0; u < 8; ++u) {
            const int tt = bb * 8 + u;
            const float* src; u16* dst; int lds_, k0, n0;
            if (tt < 768)       { src = P.W_ioux; lds_ = 1536; dst = P.WxT;
                                  k0 = (tt & 15) * 32; n0 = (tt >> 4) * 32; }
            else if (tt < 1024) { const int t2 = tt - 768; src = P.W_fx; lds_ = 512;
                                  dst = P.WxT + (size_t)1536 * 512;
                                  k0 = (t2 & 15) * 32; n0 = (t2 >> 4) * 32; }
            else if (tt < 1792) { const int t2 = tt - 1024; src = P.W_iouh; lds_ = 1536;
                                  dst = P.WiouhT; k0 = (t2 & 15) * 32; n0 = (t2 >> 4) * 32; }
            else                { const int t2 = tt - 1792; src = P.W_fh; lds_ = 512;
                                  dst = P.WfhT; k0 = (t2 & 15) * 32; n0 = (t2 >> 4) * 32; }
            __syncthreads();
#pragma unroll
            for (int i = 0; i < 4; ++i)
                smem[0][ty + 8 * i][tx] = src[(size_t)(k0 + ty + 8 * i) * lds_ + n0 + tx];
            __syncthreads();
#pragma unroll
            for (int i = 0; i < 4; ++i)
                stg16(&dst[(size_t)(n0 + ty + 8 * i) * 512 + k0 + tx], f2bf(smem[0][tx][ty + 8 * i]));
        }
        if (bb == 0) {
            for (int i = tid; i < 512; i += 256) {
                stg16(&P.hbf[(size_t)512 * 512 + i], (u16)0);
                stg16(&P.hbf[(size_t)1025 * 512 + i], (u16)0);
                stg32(&P.cbuf[(size_t)512 * 512 + i], 0.f);
                stg32(&P.cbuf[(size_t)1025 * 512 + i], 0.f);
                stg32(&P.hid_raw[i], 0.f);
            }
        }
    }
    bar_arrive(leaf);
    bar_wait(root, leaf, 32, 8, leader);           // barrier 1: all 8 groups

    // ================= S1: prege — xcat[1024][2048] = bf16(emb[tok])@WxT^T + b
    {
        const int mt = bb & 31, nb = bb >> 5;
        const int colbase = nb * 256 + w * 64;
        const int r0 = mt * 32 + m, r1 = r0 + 16;
        const int tok0 = (r0 < 512) ? P.lin[r0] : P.rin[r0 - 512];
        const int tok1 = (r1 < 512) ? P.lin[r1] : P.rin[r1 - 512];
        const float* A0 = P.emb + (size_t)tok0 * 512;
        const float* A1 = P.emb + (size_t)tok1 * 512;
        f32x4 acc[2][4];
#pragma unroll
        for (int i = 0; i < 2; ++i)
#pragma unroll
            for (int j = 0; j < 4; ++j) acc[i][j] = (f32x4){0.f, 0.f, 0.f, 0.f};
        for (int k0 = 0; k0 < 512; k0 += 32) {
            const int koff = k0 + q * 8;
            bf16x8 a0 = load_f32_as_bf8(A0 + koff);
            bf16x8 a1 = load_f32_as_bf8(A1 + koff);
#pragma unroll
            for (int jj = 0; jj < 4; ++jj) {
                bf16x8 b = *(const bf16x8*)(P.WxT + (size_t)(colbase + jj * 16 + m) * 512 + koff);
                acc[0][jj] = mfma16(a0, b, acc[0][jj]);
                acc[1][jj] = mfma16(a1, b, acc[1][jj]);
            }
        }
#pragma unroll
        for (int i = 0; i < 2; ++i)
#pragma unroll
            for (int jj = 0; jj < 4; ++jj)
#pragma unroll
                for (int rr = 0; rr < 4; ++rr) {
                    const int R = mt * 32 + i * 16 + q * 4 + rr;
                    const int col = colbase + jj * 16 + m;
                    const float bias = (col < 1536) ? P.b_ioux[col] : P.b_fx[col - 1536];
                    stg16(&P.xcat[(size_t)R * 2048 + col], f2bf(acc[i][jj][rr] + bias));
                }
    }
    bar_arrive(leaf);                               // barrier 2
    if (bb >= 64) {
        // groups 2..7 retire: leader promotes its group's arrival, then exit.
        if (leader && threadIdx.x == 0) {
            while (ald(leaf) < 64) __builtin_amdgcn_s_sleep(1);
            aadd(root);
        }
        return;
    }
    bar_wait(root, leaf, 64, 16, leader);           // groups 0,1 wait

    // ================= phases 0..5: fused gather + dual GEMM + gating ======
    constexpr int los[6] = {0, 171, 427, 491, 507, 511};
    constexpr int Bsz[6] = {171, 256, 64, 16, 4, 1};
#pragma unroll 1
    for (int ph = 0; ph < 6; ++ph) {
        const int lo = los[ph], B = Bsz[ph], B2 = 2 * B;
        const int RG = (B2 + 31) >> 5;
        if (bb < RG * 4) {
            const int rg = bb >> 2, cgp = bb & 3;
            const int colbase = cgp * 128 + w * 32;

            const u16* hpA[2][4];
#pragma unroll
            for (int Mi = 0; Mi < 2; ++Mi) {
                const int r = rg * 32 + Mi * 16 + m;
                int tree = 0, c0 = 512, c1 = 512, c2 = 512, c3 = 512;
                if (r < B2) {
                    tree = (r >= B) ? 1 : 0;
                    const int j = lo + r - tree * B;
                    const int* ch = (tree ? P.rch : P.lch) + 4 * j;
                    c0 = ch[0]; c1 = ch[1]; c2 = ch[2]; c3 = ch[3];
                }
                const u16* hb = P.hbf + (size_t)tree * 513 * 512;
                hpA[Mi][0] = hb + (size_t)c0 * 512; hpA[Mi][1] = hb + (size_t)c1 * 512;
                hpA[Mi][2] = hb + (size_t)c2 * 512; hpA[Mi][3] = hb + (size_t)c3 * 512;
            }
            const u16* fpA[8];
#pragma unroll
            for (int Ft = 0; Ft < 8; ++Ft) {
                const int fr = Ft * 16 + m;
                const int r = rg * 32 + (fr >> 2), s = fr & 3;
                int tree = 0, c = 512;
                if (r < B2) {
                    tree = (r >= B) ? 1 : 0;
                    const int j = lo + r - tree * B;
                    c = ((tree ? P.rch : P.lch) + 4 * j)[s];
                }
                fpA[Ft] = P.hbf + ((size_t)tree * 513 + c) * 512;
            }
            const u16* pBi[3][2]; const u16* pBf[2];
#pragma unroll
            for (int g = 0; g < 3; ++g)
#pragma unroll
                for (int Nj = 0; Nj < 2; ++Nj)
                    pBi[g][Nj] = P.WiouhT + (size_t)(g * 512 + colbase + Nj * 16 + m) * 512;
#pragma unroll
            for (int Nj = 0; Nj < 2; ++Nj)
                pBf[Nj] = P.WfhT + (size_t)(colbase + Nj * 16 + m) * 512;

            f32x4 aci[3][2][2];
            f32x4 acf[8][2];
#pragma unroll
            for (int g = 0; g < 3; ++g)
#pragma unroll
                for (int Mi = 0; Mi < 2; ++Mi)
#pragma unroll
                    for (int Nj = 0; Nj < 2; ++Nj) aci[g][Mi][Nj] = (f32x4){0.f, 0.f, 0.f, 0.f};
#pragma unroll
            for (int Ft = 0; Ft < 8; ++Ft)
#pragma unroll
                for (int Nj = 0; Nj < 2; ++Nj) acf[Ft][Nj] = (f32x4){0.f, 0.f, 0.f, 0.f};

#pragma unroll 1
            for (int k0 = 0; k0 < 512; k0 += 32) {
                const int koff = k0 + q * 8;
                bf16x8 ah[2];
#pragma unroll
                for (int Mi = 0; Mi < 2; ++Mi) {
                    float s0[8] = {0.f, 0.f, 0.f, 0.f, 0.f, 0.f, 0.f, 0.f};
#pragma unroll
                    for (int s = 0; s < 4; ++s) {
                        bf16x8 v = *(const bf16x8*)(hpA[Mi][s] + koff);
#pragma unroll
                        for (int t = 0; t < 8; ++t) s0[t] += (float)v[t];
                    }
                    bf16x8 a;
#pragma unroll
                    for (int t = 0; t < 8; ++t) a[t] = (__bf16)s0[t];
                    ah[Mi] = a;
                }
                bf16x8 af[8];
#pragma unroll
                for (int Ft = 0; Ft < 8; ++Ft) af[Ft] = *(const bf16x8*)(fpA[Ft] + koff);
#pragma unroll
                for (int Nj = 0; Nj < 2; ++Nj) {
#pragma unroll
                    for (int g = 0; g < 3; ++g) {
                        bf16x8 b = *(const bf16x8*)(pBi[g][Nj] + koff);
                        aci[g][0][Nj] = mfma16(ah[0], b, aci[g][0][Nj]);
                        aci[g][1][Nj] = mfma16(ah[1], b, aci[g][1][Nj]);
                    }
                    bf16x8 b2 = *(const bf16x8*)(pBf[Nj] + koff);
#pragma unroll
                    for (int Ft = 0; Ft < 8; ++Ft) acf[Ft][Nj] = mfma16(af[Ft], b2, acf[Ft][Nj]);
                }
            }

            // f epilogue: lane (q,m) owns node R=4*Ft+q, child=reg, col=Nj*16+m
#pragma unroll
            for (int Ft = 0; Ft < 8; ++Ft) {
                const int R = 4 * Ft + q;
                const int r = rg * 32 + R;
                int tree = 0, j = lo, cc0 = 512, cc1 = 512, cc2 = 512, cc3 = 512;
                if (r < B2) {
                    tree = (r >= B) ? 1 : 0;
                    j = lo + r - tree * B;
                    const int* ch = (tree ? P.rch : P.lch) + 4 * j;
                    cc0 = ch[0]; cc1 = ch[1]; cc2 = ch[2]; cc3 = ch[3];
                }
                const float* cb = P.cbuf + (size_t)tree * 513 * 512;
#pragma unroll
                for (int Nj = 0; Nj < 2; ++Nj) {
                    const int C = colbase + Nj * 16 + m;
                    const float xf = bf2f(P.xcat[(size_t)(tree * 512 + j) * 2048 + 1536 + C]);
                    const float bfh = P.b_fh[C] + xf;
                    float fs = sigm(acf[Ft][Nj][0] + bfh) * cb[(size_t)cc0 * 512 + C]
                             + sigm(acf[Ft][Nj][1] + bfh) * cb[(size_t)cc1 * 512 + C]
                             + sigm(acf[Ft][Nj][2] + bfh) * cb[(size_t)cc2 * 512 + C]
                             + sigm(acf[Ft][Nj][3] + bfh) * cb[(size_t)cc3 * 512 + C];
                    smem[w][R][Nj * 16 + m] = fs;
                }
            }
            __syncthreads();
            // gating epilogue: lane (q,m), row R = Mi*16+q*4+rr
#pragma unroll
            for (int Mi = 0; Mi < 2; ++Mi)
#pragma unroll
                for (int rr = 0; rr < 4; ++rr) {
                    const int R = Mi * 16 + q * 4 + rr;
                    const int r = rg * 32 + R;
                    if (r >= B2) continue;
                    const int tree = (r >= B) ? 1 : 0;
                    const int j = lo + r - tree * B;
                    const size_t xrow = (size_t)(tree * 512 + j) * 2048;
#pragma unroll
                    for (int Nj = 0; Nj < 2; ++Nj) {
                        const int C = colbase + Nj * 16 + m;
                        const float ii = aci[0][Mi][Nj][rr] + P.b_iouh[C]        + bf2f(P.xcat[xrow + C]);
                        const float oo = aci[1][Mi][Nj][rr] + P.b_iouh[512 + C]  + bf2f(P.xcat[xrow + 512 + C]);
                        const float uu = aci[2][Mi][Nj][rr] + P.b_iouh[1024 + C] + bf2f(P.xcat[xrow + 1024 + C]);
                        const float ig = sigm(ii), og = sigm(oo), ug = tanhf(uu);
                        const float cv = ig * ug + smem[w][R][Nj * 16 + m];
                        stg32(&P.cbuf[((size_t)tree * 513 + j) * 512 + C], cv);
                        stg16(&P.hbf[((size_t)tree * 513 + j) * 512 + C], f2bf(og * tanhf(cv)));
                    }
                }
        }
        bar_arrive(leaf);                           // barriers 3..8
        bar_wait(root, leaf, 96 + 32 * ph, 18 + 2 * ph, leader);
    }

    // ================= head1: hid_raw[col] += vec @ Wh ======================
    {
        const float* lc = P.cbuf + (size_t)511 * 512;
        const float* rc = P.cbuf + (size_t)(513 + 511) * 512;
        const int cg8 = bb & 7, kg = bb >> 3;
        const int col = cg8 * 64 + lane;
        const int kbase = kg * 128 + w * 32;
        float acc = 0.f;
#pragma unroll 8
        for (int i = 0; i < 32; ++i) {
            const int k = kbase + i;
            float v;
            if (k < 512) v = lc[k] * rc[k];
            else { const int kk = k - 512; v = fabsf(lc[kk] - rc[kk]); }
            acc += v * P.Wh[(size_t)k * 512 + col];
        }
        smem[w][0][lane] = acc;
        __syncthreads();
        if (w == 0)
            __hip_atomic_fetch_add(&P.hid_raw[col],
                smem[0][0][lane] + smem[1][0][lane] + smem[2][0][lane] + smem[3][0][lane],
                __ATOMIC_RELAXED, __HIP_MEMORY_SCOPE_AGENT);
    }
    bar_arrive(leaf);                               // barrier 9
    if (bb != 0) {
        if (leader && threadIdx.x == 0) {           // bb==32: promote group 1
            while (ald(leaf) < 288) __builtin_amdgcn_s_sleep(1);
            aadd(root);
        }
        return;
    }
    bar_wait(root, leaf, 288, 30, true);            // bb==0 promotes group 0

    // ================= head2: log_softmax(sigm(hid)@Wp + bp) ================
    {
        float a[5] = {0.f, 0.f, 0.f, 0.f, 0.f};
        for (int k = tid; k < 512; k += 256) {
            const float hv = sigm(P.hid_raw[k] + P.bh[k]);
#pragma unroll
            for (int cc = 0; cc < 5; ++cc) a[cc] += hv * P.Wp[(size_t)k * 5 + cc];
        }
#pragma unroll
        for (int cc = 0; cc < 5; ++cc)
            for (int off = 32; off; off >>= 1) a[cc] += __shfl_xor(a[cc], off, 64);
        if (lane == 0)
#pragma unroll
            for (int cc = 0; cc < 5; ++cc) smem[w][1][cc] = a[cc];
        __syncthreads();
        if (tid == 0) {
            float lg[5], mx = -1e30f;
#pragma unroll
            for (int cc = 0; cc < 5; ++cc) {
                lg[cc] = smem[0][1][cc] + smem[1][1][cc] + smem[2][1][cc] + smem[3][1][cc] + P.bp[cc];
                mx = fmaxf(mx, lg[cc]);
            }
            float s = 0.f;
#pragma unroll
            for (int cc = 0; cc < 5; ++cc) s += __expf(lg[cc] - mx);
            const float lse = mx + __logf(s);
#pragma unroll
            for (int cc = 0; cc < 5; ++cc) P.out[cc] = lg[cc] - lse;
        }
    }
}

// ---------------- launch ----------------------------------------------------
extern "C" void kernel_launch(void* const* d_in, const int* in_sizes, int n_in,
                              void* d_out, int out_size, void* d_ws, size_t ws_size,
                              hipStream_t stream)
{
    Params P;
    P.lin    = (const int*)d_in[0];
    P.rin    = (const int*)d_in[1];
    P.lch    = (const int*)d_in[2];
    P.rch    = (const int*)d_in[3];
    P.emb    = (const float*)d_in[4];
    P.W_ioux = (const float*)d_in[5];
    P.b_ioux = (const float*)d_in[6];
    P.W_iouh = (const float*)d_in[7];
    P.b_iouh = (const float*)d_in[8];
    P.W_fx   = (const float*)d_in[9];
    P.b_fx   = (const float*)d_in[10];
    P.W_fh   = (const float*)d_in[11];
    P.b_fh   = (const float*)d_in[12];
    P.Wh     = (const float*)d_in[13];
    P.bh     = (const float*)d_in[14];
    P.Wp     = (const float*)d_in[15];
    P.bp     = (const float*)d_in[16];
    P.out    = (float*)d_out;
    (void)ws_size; (void)n_in; (void)in_sizes; (void)out_size;

    char* p = (char*)d_ws;
    P.WiouhT  = (u16*)p;   p += (size_t)1536 * 512 * 2;
    P.WfhT    = (u16*)p;   p += (size_t)512 * 512 * 2;
    P.WxT     = (u16*)p;   p += (size_t)2048 * 512 * 2;
    P.xcat    = (u16*)p;   p += (size_t)1024 * 2048 * 2;
    P.hbf     = (u16*)p;   p += (size_t)2 * 513 * 512 * 2;
    P.cbuf    = (float*)p; p += (size_t)2 * 513 * 512 * 4;
    P.hid_raw = (float*)p; p += (size_t)512 * 4;
    P.bar     = (unsigned*)p; p += 1024;

    hipMemsetAsync(P.bar, 0, 1024, stream);
    fused<<<NB, 256, 0, stream>>>(P);
}